// Round 6
// baseline (221.145 us; speedup 1.0000x reference)
//
#include <hip/hip_runtime.h>
#include <math.h>

#define B_N 8192
#define D_N 512
#define S_N 5
#define C_N 2048
#define H_N 4

typedef __attribute__((ext_vector_type(8))) short bf16x8;
typedef __attribute__((ext_vector_type(4))) float floatx4;

__device__ __forceinline__ float bf2f(short u) {
  union { unsigned int i; float f; } c;
  c.i = ((unsigned int)(unsigned short)u) << 16;
  return c.f;
}
__device__ __forceinline__ short f2bf(float f) {
  union { float f; unsigned int i; } c; c.f = f;
  unsigned int x = c.i;
  x += 0x7fffu + ((x >> 16) & 1u);   // round-to-nearest-even
  return (short)(x >> 16);
}
__device__ __forceinline__ unsigned long long pack4(float a, float b, float c, float d) {
  return (unsigned long long)(unsigned short)f2bf(a)
       | ((unsigned long long)(unsigned short)f2bf(b) << 16)
       | ((unsigned long long)(unsigned short)f2bf(c) << 32)
       | ((unsigned long long)(unsigned short)f2bf(d) << 48);
}

// ---------------- pre: f->bf16 cvt + weight copies + u/v/c ----------------
// blocks 0..2047: cvt f; 2048..2079: Wq->bf16; 2080..2111: Wk->bf16;
// 2112: u[ha] = bq_h . Wk[a, h*128:+128]; 2113: v[d][h] = Wq[d,h*128:+128].bk_h, c[h]=bq_h.bk_h
__global__ __launch_bounds__(256) void k_pre(
    const float* __restrict__ f, const float* __restrict__ Wq,
    const float* __restrict__ Wk, const float* __restrict__ bq,
    const float* __restrict__ bk, short* __restrict__ fbf,
    short* __restrict__ Wqb, short* __restrict__ Wkb,
    float* __restrict__ u, float* __restrict__ v, float* __restrict__ c) {
  const int bx = blockIdx.x, t = threadIdx.x;
  if (bx < 2048) {
    int i = bx * 256 + t;
    const floatx4* p = (const floatx4*)(f + (size_t)i * 8);
    floatx4 a = p[0], b = p[1];
    *(unsigned long long*)(fbf + (size_t)i * 8)     = pack4(a[0], a[1], a[2], a[3]);
    *(unsigned long long*)(fbf + (size_t)i * 8 + 4) = pack4(b[0], b[1], b[2], b[3]);
  } else if (bx < 2112) {
    const float* src = (bx < 2080) ? Wq : Wk;
    short* dst = (bx < 2080) ? Wqb : Wkb;
    const int base = ((bx < 2080) ? (bx - 2048) : (bx - 2080)) * 8192 + t * 4;
#pragma unroll
    for (int i = 0; i < 8; ++i) {
      int idx = base + i * 1024;
      floatx4 w4 = *(const floatx4*)(src + idx);
      *(unsigned long long*)(dst + idx) = pack4(w4[0], w4[1], w4[2], w4[3]);
    }
  } else if (bx == 2112) {
#pragma unroll
    for (int i = 0; i < 8; ++i) {
      int o = i * 256 + t;
      int h = o >> 9, a = o & 511;
      const float* wkr = Wk + (size_t)a * 512 + h * 128;
      const float* bqr = bq + h * 128;
      float s = 0.0f;
#pragma unroll 4
      for (int j = 0; j < 128; j += 4) {
        floatx4 w4 = *(const floatx4*)(wkr + j);
        floatx4 b4 = *(const floatx4*)(bqr + j);
        s += w4[0]*b4[0] + w4[1]*b4[1] + w4[2]*b4[2] + w4[3]*b4[3];
      }
      u[o] = s;
    }
  } else {
#pragma unroll
    for (int i = 0; i < 8; ++i) {
      int o = i * 256 + t;
      int d = o >> 2, h = o & 3;
      const float* wqr = Wq + (size_t)d * 512 + h * 128;
      const float* bkr = bk + h * 128;
      float s = 0.0f;
#pragma unroll 4
      for (int j = 0; j < 128; j += 4) {
        floatx4 w4 = *(const floatx4*)(wqr + j);
        floatx4 b4 = *(const floatx4*)(bkr + j);
        s += w4[0]*b4[0] + w4[1]*b4[1] + w4[2]*b4[2] + w4[3]*b4[3];
      }
      v[o] = s;
    }
    if (t < H_N) {
      const float* bqr = bq + t * 128;
      const float* bkr = bk + t * 128;
      float s = 0.0f;
      for (int j = 0; j < 128; ++j) s += bqr[j] * bkr[j];
      c[t] = s;
    }
  }
}

// ---------------- MFMA GEMM (round-1 verbatim, passed) ----------------
__device__ __forceinline__ void gll(const short* g, short* l) {
  __builtin_amdgcn_global_load_lds(
      (const __attribute__((address_space(1))) unsigned int*)(g),
      (__attribute__((address_space(3))) unsigned int*)(l), 16, 0, 0);
}

__global__ __launch_bounds__(256) void k_gemm(
    const short* __restrict__ A, int lda,
    const short* __restrict__ BT, int ldb,
    short* __restrict__ O, int ldo,
    const float* __restrict__ bias, int K, int z_koff, int z_coff) {
  __shared__ __align__(16) short As[2][4096];
  __shared__ __align__(16) short Bs[2][4096];

  const int tid = threadIdx.x;
  const int lane = tid & 63;
  const int wid = tid >> 6;
  const int wr = wid >> 1, wc = wid & 1;
  const int row0 = blockIdx.y * 128;
  const int col0 = blockIdx.x * 128;
  const int z = blockIdx.z;
  const int koff = z * z_koff;
  const int ocoff = z * z_coff;

  const int r1 = tid >> 2, hk = tid & 3;
  const short* Ag1 = A + (size_t)(row0 + r1) * lda + koff + hk * 8;
  const short* Ag2 = A + (size_t)(row0 + 64 + r1) * lda + koff + hk * 8;
  const short* Bg1 = BT + (size_t)(col0 + r1) * ldb + koff + hk * 8;
  const short* Bg2 = BT + (size_t)(col0 + 64 + r1) * ldb + koff + hk * 8;

  floatx4 acc[4][4];
  const floatx4 zero = {0.0f, 0.0f, 0.0f, 0.0f};
#pragma unroll
  for (int m = 0; m < 4; ++m)
#pragma unroll
    for (int n = 0; n < 4; ++n) acc[m][n] = zero;

  const int NT = K >> 5;
  int cur = 0;

  auto stage = [&](int q, int kb) {
    gll(Ag1 + kb, &As[q][tid * 8]);
    gll(Ag2 + kb, &As[q][tid * 8 + 2048]);
    gll(Bg1 + kb, &Bs[q][tid * 8]);
    gll(Bg2 + kb, &Bs[q][tid * 8 + 2048]);
  };

  stage(0, 0);
  __syncthreads();

  for (int t = 0; t < NT; ++t) {
    if (t + 1 < NT) stage(cur ^ 1, (t + 1) * 32);
    bf16x8 af[4], bfr[4];
#pragma unroll
    for (int m = 0; m < 4; ++m)
      af[m] = *(const bf16x8*)&As[cur][(wr * 64 + m * 16 + (lane & 15)) * 32 + (lane >> 4) * 8];
#pragma unroll
    for (int n = 0; n < 4; ++n)
      bfr[n] = *(const bf16x8*)&Bs[cur][(wc * 64 + n * 16 + (lane & 15)) * 32 + (lane >> 4) * 8];
#pragma unroll
    for (int m = 0; m < 4; ++m)
#pragma unroll
      for (int n = 0; n < 4; ++n)
        acc[m][n] = __builtin_amdgcn_mfma_f32_16x16x32_bf16(af[m], bfr[n], acc[m][n], 0, 0, 0);
    __syncthreads();
    cur ^= 1;
  }

#pragma unroll
  for (int m = 0; m < 4; ++m) {
    int rowb = row0 + wr * 64 + m * 16 + (lane >> 4) * 4;
#pragma unroll
    for (int n = 0; n < 4; ++n) {
      int lcol = col0 + wc * 64 + n * 16 + (lane & 15);
      float bv = bias ? bias[lcol] : 0.0f;
      int ocol = ocoff + lcol;
#pragma unroll
      for (int j = 0; j < 4; ++j) {
        O[(size_t)(rowb + j) * ldo + ocol] = f2bf(acc[m][n][j] + bv);
      }
    }
  }
}

// ---------------- k_gemmM: identical loop, TRANSPOSED epilogue (writes O[col][row]) ----
__global__ __launch_bounds__(256) void k_gemmM(
    const short* __restrict__ A, int lda,
    const short* __restrict__ BT, int ldb,
    short* __restrict__ O, int ldo,
    int K, int z_koff, int z_coff) {
  __shared__ __align__(16) short As[2][4096];
  __shared__ __align__(16) short Bs[2][4096];

  const int tid = threadIdx.x;
  const int lane = tid & 63;
  const int wid = tid >> 6;
  const int wr = wid >> 1, wc = wid & 1;
  const int row0 = blockIdx.y * 128;
  const int col0 = blockIdx.x * 128;
  const int z = blockIdx.z;
  const int koff = z * z_koff;
  const int ocoff = z * z_coff;

  const int r1 = tid >> 2, hk = tid & 3;
  const short* Ag1 = A + (size_t)(row0 + r1) * lda + koff + hk * 8;
  const short* Ag2 = A + (size_t)(row0 + 64 + r1) * lda + koff + hk * 8;
  const short* Bg1 = BT + (size_t)(col0 + r1) * ldb + koff + hk * 8;
  const short* Bg2 = BT + (size_t)(col0 + 64 + r1) * ldb + koff + hk * 8;

  floatx4 acc[4][4];
  const floatx4 zero = {0.0f, 0.0f, 0.0f, 0.0f};
#pragma unroll
  for (int m = 0; m < 4; ++m)
#pragma unroll
    for (int n = 0; n < 4; ++n) acc[m][n] = zero;

  const int NT = K >> 5;
  int cur = 0;

  auto stage = [&](int q, int kb) {
    gll(Ag1 + kb, &As[q][tid * 8]);
    gll(Ag2 + kb, &As[q][tid * 8 + 2048]);
    gll(Bg1 + kb, &Bs[q][tid * 8]);
    gll(Bg2 + kb, &Bs[q][tid * 8 + 2048]);
  };

  stage(0, 0);
  __syncthreads();

  for (int t = 0; t < NT; ++t) {
    if (t + 1 < NT) stage(cur ^ 1, (t + 1) * 32);
    bf16x8 af[4], bfr[4];
#pragma unroll
    for (int m = 0; m < 4; ++m)
      af[m] = *(const bf16x8*)&As[cur][(wr * 64 + m * 16 + (lane & 15)) * 32 + (lane >> 4) * 8];
#pragma unroll
    for (int n = 0; n < 4; ++n)
      bfr[n] = *(const bf16x8*)&Bs[cur][(wc * 64 + n * 16 + (lane & 15)) * 32 + (lane >> 4) * 8];
#pragma unroll
    for (int m = 0; m < 4; ++m)
#pragma unroll
      for (int n = 0; n < 4; ++n)
        acc[m][n] = __builtin_amdgcn_mfma_f32_16x16x32_bf16(af[m], bfr[n], acc[m][n], 0, 0, 0);
    __syncthreads();
    cur ^= 1;
  }

  // transposed write: O[(ocoff+col)][row]
#pragma unroll
  for (int m = 0; m < 4; ++m) {
    int rowb = row0 + wr * 64 + m * 16 + (lane >> 4) * 4;
#pragma unroll
    for (int n = 0; n < 4; ++n) {
      int ocol = ocoff + col0 + wc * 64 + n * 16 + (lane & 15);
#pragma unroll
      for (int j = 0; j < 4; ++j) {
        O[(size_t)ocol * ldo + rowb + j] = f2bf(acc[m][n][j]);
      }
    }
  }
}

// ---------------- fused stats + attention + logits mix (1 wave per row) ----------------
// grid 2048 x 256 thr; wave w -> row b = blockIdx*4 + w. ZERO LDS, ZERO barriers.
__global__ __launch_bounds__(256, 4) void k_fused(
    const float* __restrict__ f, const float* __restrict__ sf,
    const float* __restrict__ emb, const short* __restrict__ Rbf,
    const float* __restrict__ vbuf, const float* __restrict__ cbuf,
    const float* __restrict__ temp, const float* __restrict__ attn_w,
    const float* __restrict__ logits, float* __restrict__ out,
    float* __restrict__ comb_out) {
  const int lane = threadIdx.x & 63;
  const int wid = threadIdx.x >> 6;
  const int b = blockIdx.x * 4 + wid;
  const int a0 = lane * 8;

  // ---- per-lane f slice + ff partial ----
  const floatx4* fp = (const floatx4*)(f + (size_t)b * D_N + a0);
  floatx4 fA = fp[0], fB = fp[1];
  float fv[8];
#pragma unroll
  for (int j = 0; j < 4; ++j) { fv[j] = fA[j]; fv[4 + j] = fB[j]; }
  float ffp = 0;
#pragma unroll
  for (int j = 0; j < 8; ++j) ffp += fv[j] * fv[j];

  // ---- qbk[h] = f . v[:,h] (+ c[h]); v is [512][4] f32, L2-resident ----
  float cinit[H_N];
  {
    float qbk[H_N] = {0, 0, 0, 0};
    const floatx4* vp = (const floatx4*)(vbuf + (size_t)a0 * 4);
#pragma unroll
    for (int j = 0; j < 8; ++j) {
      floatx4 vv = vp[j];
#pragma unroll
      for (int h = 0; h < H_N; ++h) qbk[h] += fv[j] * vv[h];
    }
#pragma unroll
    for (int h = 0; h < H_N; ++h)
      cinit[h] = qbk[h] + (lane == 0 ? cbuf[h] : 0.0f);
  }

  float rf[H_N][8];
#pragma unroll
  for (int h = 0; h < H_N; ++h) {
    bf16x8 rv = *(const bf16x8*)(Rbf + (size_t)b * 2048 + h * 512 + a0);
#pragma unroll
    for (int j = 0; j < 8; ++j) rf[h][j] = bf2f(rv[j]);
  }

  float fs_[S_N], ss_[S_N], sc_[S_N][H_N];

#pragma unroll
  for (int s = 0; s < S_N; ++s) {
    const floatx4* sp = (const floatx4*)(sf + ((size_t)s * B_N + b) * D_N + a0);
    floatx4 sA = sp[0], sB = sp[1];
    const floatx4* ep = (const floatx4*)(emb + (size_t)s * D_N + a0);
    floatx4 eA = ep[0], eB = ep[1];
    float sv[8], se[8];
#pragma unroll
    for (int j = 0; j < 4; ++j) {
      sv[j] = sA[j]; sv[4 + j] = sB[j];
      se[j] = sA[j] + eA[j]; se[4 + j] = sB[j] + eB[j];
    }
    float fsp = 0, ssp = 0;
    float scp[H_N];
#pragma unroll
    for (int h = 0; h < H_N; ++h) scp[h] = cinit[h];
#pragma unroll
    for (int j = 0; j < 8; ++j) {
      fsp += fv[j] * sv[j];
      ssp += sv[j] * sv[j];
#pragma unroll
      for (int h = 0; h < H_N; ++h) scp[h] += se[j] * rf[h][j];
    }
#pragma unroll
    for (int o = 1; o < 64; o <<= 1) {
      fsp += __shfl_xor(fsp, o, 64);
      ssp += __shfl_xor(ssp, o, 64);
#pragma unroll
      for (int h = 0; h < H_N; ++h) scp[h] += __shfl_xor(scp[h], o, 64);
    }
    fs_[s] = fsp; ss_[s] = ssp;
#pragma unroll
    for (int h = 0; h < H_N; ++h) sc_[s][h] = scp[h];
  }
  float ffv = ffp;
#pragma unroll
  for (int o = 1; o < 64; o <<= 1) ffv += __shfl_xor(ffv, o, 64);

  // NOTE: cinit added per-lane then butterfly-summed => qbk counted once (distinct d per lane), c via lane 0. ✓

  // ---- finalize (all lanes redundantly, wave-uniform) ----
  const float t = fabsf(temp[0]);

  float amha[S_N] = {0, 0, 0, 0, 0};
  const float inv_mha = 1.0f / (sqrtf(128.0f) * t);
#pragma unroll
  for (int h = 0; h < H_N; ++h) {
    float lg[S_N];
#pragma unroll
    for (int s = 0; s < S_N; ++s) lg[s] = sc_[s][h] * inv_mha;
    float mx = lg[0];
#pragma unroll
    for (int s = 1; s < S_N; ++s) mx = fmaxf(mx, lg[s]);
    float e[S_N], sum = 0;
#pragma unroll
    for (int s = 0; s < S_N; ++s) { e[s] = __expf(lg[s] - mx); sum += e[s]; }
    float isum = 0.25f / sum;
#pragma unroll
    for (int s = 0; s < S_N; ++s) amha[s] += e[s] * isum;
  }

  float ageo[S_N];
  {
    const float nf = fmaxf(sqrtf(ffv), 1e-12f);
    float g[S_N];
#pragma unroll
    for (int s = 0; s < S_N; ++s) {
      float ns = fmaxf(sqrtf(ss_[s]), 1e-12f);
      float cs0 = fs_[s] / (nf * ns);
      cs0 = fminf(fmaxf(cs0, -1.0f + 1e-7f), 1.0f - 1e-7f);
      g[s] = __expf(-acosf(cs0) / t);
    }
    float mx = g[0];
#pragma unroll
    for (int s = 1; s < S_N; ++s) mx = fmaxf(mx, g[s]);
    float sum = 0;
#pragma unroll
    for (int s = 0; s < S_N; ++s) { ageo[s] = __expf(g[s] - mx); sum += ageo[s]; }
#pragma unroll
    for (int s = 0; s < S_N; ++s) ageo[s] /= sum;
  }

  float acay[S_N];
  {
    const float SQ2 = 1.41421356237309515f;
    const float Aff = 0.72f;
    const float Ass = 0.72f - 0.32f * SQ2;
    const float Afs = -(8.0f + 4.0f * SQ2) / 25.0f;
    float lg[S_N];
#pragma unroll
    for (int s = 0; s < S_N; ++s)
      lg[s] = (Aff * ffv + Ass * ss_[s] + Afs * fs_[s]) / t;
    float mx = lg[0];
#pragma unroll
    for (int s = 1; s < S_N; ++s) mx = fmaxf(mx, lg[s]);
    float sum = 0;
#pragma unroll
    for (int s = 0; s < S_N; ++s) { acay[s] = __expf(lg[s] - mx); sum += acay[s]; }
#pragma unroll
    for (int s = 0; s < S_N; ++s) acay[s] /= sum;
  }

  float w0 = attn_w[0], w1 = attn_w[1], w2 = attn_w[2];
  float wm = fmaxf(w0, fmaxf(w1, w2));
  float e0 = __expf(w0 - wm), e1 = __expf(w1 - wm), e2 = __expf(w2 - wm);
  float wsum = e0 + e1 + e2;
  w0 = e0 / wsum; w1 = e1 / wsum; w2 = e2 / wsum;

  float cb[S_N], csum = 0;
#pragma unroll
  for (int s = 0; s < S_N; ++s) {
    cb[s] = w0 * amha[s] + w1 * ageo[s] + w2 * acay[s];
    csum += cb[s];
  }
  float ic = 1.0f / csum;
  float cbn[S_N];
#pragma unroll
  for (int s = 0; s < S_N; ++s) cbn[s] = cb[s] * ic;
  if (lane == 0) {
#pragma unroll
    for (int s = 0; s < S_N; ++s) comb_out[(size_t)b * S_N + s] = cbn[s];
  }

  // ---- mix tail ----
  const floatx4 fz = {0.f, 0.f, 0.f, 0.f};
#pragma unroll
  for (int cj = 0; cj < 4; ++cj) {
    const int c0 = cj * 512 + lane * 8;
    floatx4 accA = fz, accB = fz;
#pragma unroll
    for (int s = 0; s < S_N; ++s) {
      const float* lp = logits + ((size_t)s * B_N + b) * C_N + c0;
      floatx4 lA = *(const floatx4*)lp;
      floatx4 lB = *(const floatx4*)(lp + 4);
      accA += lA * cbn[s];
      accB += lB * cbn[s];
    }
    float* op = out + (size_t)b * C_N + c0;
    *(floatx4*)op = accA;
    *(floatx4*)(op + 4) = accB;
  }
}

extern "C" void kernel_launch(void* const* d_in, const int* in_sizes, int n_in,
                              void* d_out, int out_size, void* d_ws, size_t ws_size,
                              hipStream_t stream) {
  const float* features = (const float*)d_in[0];
  const float* logits   = (const float*)d_in[1];
  const float* sf       = (const float*)d_in[2];
  const float* Wq       = (const float*)d_in[3];
  const float* bq       = (const float*)d_in[4];
  const float* Wk       = (const float*)d_in[5];
  const float* bk       = (const float*)d_in[6];
  const float* emb      = (const float*)d_in[9];
  const float* temp     = (const float*)d_in[10];
  const float* attn_w   = (const float*)d_in[11];

  float* out  = (float*)d_out;
  float* comb = out + (size_t)B_N * C_N;

  char* w = (char*)d_ws;
  short* fbf = (short*)(w);                    // 8192*512  bf16 =  8.39 MB
  short* Wqb = (short*)(w + 8388608);          // 512*512   bf16 =  0.52 MB
  short* Wkb = (short*)(w + 8912896);          // 512*512   bf16 =  0.52 MB
  short* MT  = (short*)(w + 9437184);          // 2048*512  bf16 =  2.10 MB (M_h transposed)
  float* ub  = (float*)(w + 11534336);         // 2048 f32
  float* vb  = (float*)(w + 11542528);         // 512*4 f32
  float* cb  = (float*)(w + 11550720);         // 4 f32
  short* Rbf = (short*)(w + 16777216);         // 8192*2048 bf16 = 33.55 MB

  // 1. f->bf16 + weight bf16 copies + u/v/c (one kernel)
  k_pre<<<dim3(2114), dim3(256), 0, stream>>>(features, Wq, Wk, bq, bk,
                                              fbf, Wqb, Wkb, ub, vb, cb);
  // 2. MT[h*512+a][d] = M_h[d,a] = sum_j Wq[d,h*128+j]*Wk[a,h*128+j]  (K=128, transposed write)
  k_gemmM<<<dim3(4, 4, 4), dim3(256), 0, stream>>>(Wqb, 512, Wkb, 512, MT, 512,
                                                   128, 128, 512);
  // 3. R[b][ha] = sum_d fbf[b,d]*MT[ha,d] + u[ha]   (single K=512 GEMM, 1024 blocks)
  k_gemm<<<dim3(16, 64, 1), dim3(256), 0, stream>>>(fbf, 512, MT, 512, Rbf, 2048,
                                                    ub, 512, 0, 0);
  // 4. fused stats + attentions + fuse + logits mix (1 wave per row, no LDS/barriers)
  k_fused<<<dim3(2048), dim3(256), 0, stream>>>(features, sf, emb, Rbf, vb, cb,
                                                temp, attn_w, logits, out, comb);
}

// Round 7
// 169.919 us; speedup vs baseline: 1.3015x; 1.3015x over previous
//
#include <hip/hip_runtime.h>
#include <math.h>

#define B_N 8192
#define D_N 512
#define S_N 5
#define C_N 2048
#define H_N 4
#define RB 16          // rows per mega block

typedef __attribute__((ext_vector_type(8))) short bf16x8;
typedef __attribute__((ext_vector_type(4))) float floatx4;

__device__ __forceinline__ float bf2f(short u) {
  union { unsigned int i; float f; } c;
  c.i = ((unsigned int)(unsigned short)u) << 16;
  return c.f;
}
__device__ __forceinline__ short f2bf(float f) {
  union { float f; unsigned int i; } c; c.f = f;
  unsigned int x = c.i;
  x += 0x7fffu + ((x >> 16) & 1u);   // round-to-nearest-even
  return (short)(x >> 16);
}
__device__ __forceinline__ unsigned long long pack4(float a, float b, float c, float d) {
  return (unsigned long long)(unsigned short)f2bf(a)
       | ((unsigned long long)(unsigned short)f2bf(b) << 16)
       | ((unsigned long long)(unsigned short)f2bf(c) << 32)
       | ((unsigned long long)(unsigned short)f2bf(d) << 48);
}

// ---------------- weight prep (verified rounds 2-5) ----------------
__global__ __launch_bounds__(256) void k_prep(const float* __restrict__ Wq,
                                              const float* __restrict__ Wk,
                                              short* __restrict__ WqT,
                                              short* __restrict__ Wkb) {
  __shared__ float lds[64][65];
  const int bx = blockIdx.x, t = threadIdx.x;
  if (bx < 64) {
    const int r0 = (bx >> 3) * 64, c0 = (bx & 7) * 64;
#pragma unroll
    for (int i = 0; i < 16; ++i) {
      int r = i * 4 + (t >> 6), c = t & 63;
      lds[r][c] = Wq[(size_t)(r0 + r) * 512 + c0 + c];
    }
    __syncthreads();
#pragma unroll
    for (int i = 0; i < 16; ++i) {
      int cL = i * 4 + (t >> 6), rL = t & 63;
      WqT[(size_t)(c0 + cL) * 512 + r0 + rL] = f2bf(lds[rL][cL]);
    }
  } else {
    const int base = (bx - 64) * 8192 + t * 4;
#pragma unroll
    for (int i = 0; i < 8; ++i) {
      int idx = base + i * 1024;
      floatx4 v = *(const floatx4*)(Wk + idx);
      *(unsigned long long*)(Wkb + idx) = pack4(v[0], v[1], v[2], v[3]);
    }
  }
}

// ---------------- mega: cvt + Q + R + scores + stats + softmaxes -> combined ----------------
// round-3 kernel with the mix phase removed. grid 512 x RB=16 rows, 256 thr, 2 blocks/CU.
__global__ __launch_bounds__(256, 2) void k_mega(
    const float* __restrict__ f, const float* __restrict__ sf,
    const float* __restrict__ emb, const short* __restrict__ WqT,
    const short* __restrict__ Wkb, const float* __restrict__ bq,
    const float* __restrict__ bk, const float* __restrict__ temp,
    const float* __restrict__ attn_w, float* __restrict__ comb_out) {
  __shared__ __align__(16) float fLds[RB * 512];     // 32 KB, f32, XOR-swizzled rows
  __shared__ __align__(16) short Qbf[RB * 512];      // 16 KB, bf16, XOR-swizzled rows
  __shared__ __align__(16) short sfe[S_N * RB * 132];// 21120 B, pitch 264 B
  __shared__ float ffLds[RB];
  __shared__ float qtLds[RB][H_N];
  __shared__ float scLds[RB][H_N][S_N];
  __shared__ float fsLds[S_N][RB];
  __shared__ float ssLds[S_N][RB];

  const int tid = threadIdx.x;
  const int lane = tid & 63;
  const int wid = tid >> 6;
  const int b0 = blockIdx.x * RB;
  const floatx4 fz = {0.f, 0.f, 0.f, 0.f};

  // ========= phase 0: f -> fLds (f32, swizzled) + ff =========
  {
    const int r0 = tid >> 4;
    const int c0 = (tid & 15) * 32;
    const float* fp = f + (size_t)(b0 + r0) * D_N + c0;
    char* fb = (char*)fLds;
    float ffp = 0.0f;
#pragma unroll
    for (int i = 0; i < 8; ++i) {
      floatx4 v = *(const floatx4*)(fp + i * 4);
      ffp += v[0]*v[0] + v[1]*v[1] + v[2]*v[2] + v[3]*v[3];
      int bo = (r0 * 2048 + (c0 + i * 4) * 4) ^ ((r0 & 7) << 4);
      *(floatx4*)(fb + bo) = v;
    }
    ffp += __shfl_xor(ffp, 1, 64);
    ffp += __shfl_xor(ffp, 2, 64);
    ffp += __shfl_xor(ffp, 4, 64);
    ffp += __shfl_xor(ffp, 8, 64);
    if ((tid & 15) == 0) ffLds[r0] = ffp;
  }
  __syncthreads();

  // ========= phase 1: Q = bf16(f) @ WqT (+bq); q~ = Q.bk; Q -> Qbf (swizzled) =========
  {
    const int wcol0 = wid * 128;
    floatx4 acc[8];
#pragma unroll
    for (int n = 0; n < 8; ++n) acc[n] = fz;
    const char* fb = (const char*)fLds;
    const int row = lane & 15;

    for (int ks = 0; ks < 16; ++ks) {
      bf16x8 bfr[8];
#pragma unroll
      for (int n = 0; n < 8; ++n) {
        int col = wcol0 + n * 16 + (lane & 15);
        bfr[n] = *(const bf16x8*)(WqT + (size_t)col * 512 + ks * 32 + (lane >> 4) * 8);
      }
      int kbase = ks * 32 + (lane >> 4) * 8;
      int bo0 = (row * 2048 + kbase * 4) ^ ((row & 7) << 4);
      int bo1 = (row * 2048 + kbase * 4 + 16) ^ ((row & 7) << 4);
      floatx4 a0 = *(const floatx4*)(fb + bo0);
      floatx4 a1 = *(const floatx4*)(fb + bo1);
      bf16x8 afr;
      afr[0] = f2bf(a0[0]); afr[1] = f2bf(a0[1]); afr[2] = f2bf(a0[2]); afr[3] = f2bf(a0[3]);
      afr[4] = f2bf(a1[0]); afr[5] = f2bf(a1[1]); afr[6] = f2bf(a1[2]); afr[7] = f2bf(a1[3]);
#pragma unroll
      for (int n = 0; n < 8; ++n)
        acc[n] = __builtin_amdgcn_mfma_f32_16x16x32_bf16(afr, bfr[n], acc[n], 0, 0, 0);
    }

    float bqv[8], bkv[8];
#pragma unroll
    for (int n = 0; n < 8; ++n) {
      int col = wcol0 + n * 16 + (lane & 15);
      bqv[n] = bq[col];
      bkv[n] = bk[col];
    }
#pragma unroll
    for (int j = 0; j < 4; ++j) {
      int orow = (lane >> 4) * 4 + j;
      float qp = 0.0f;
#pragma unroll
      for (int n = 0; n < 8; ++n) {
        float qv = acc[n][j] + bqv[n];
        int col = wcol0 + n * 16 + (lane & 15);
        int bo = (orow * 1024 + col * 2) ^ ((orow & 7) << 4);
        *(short*)((char*)Qbf + bo) = f2bf(qv);
        qp += qv * bkv[n];
      }
      qp += __shfl_xor(qp, 1, 64);
      qp += __shfl_xor(qp, 2, 64);
      qp += __shfl_xor(qp, 4, 64);
      qp += __shfl_xor(qp, 8, 64);
      if ((lane & 15) == 0) qtLds[orow][wid] = qp;
    }
  }
  __syncthreads();

  // ========= phase 2: 4 x 128-col chunks: stage sfe + ss/fs; R-MFMA + consume =========
  float scp[S_N][4];
#pragma unroll
  for (int s = 0; s < S_N; ++s)
#pragma unroll
    for (int j = 0; j < 4; ++j) scp[s][j] = 0.0f;
  float ssp[S_N] = {0, 0, 0, 0, 0}, fsp[S_N] = {0, 0, 0, 0, 0};

  const int h = wid;
  for (int cc = 0; cc < 4; ++cc) {
    // ---- 2a: stage sfe chunk (bf16) + ss/fs partials (f32; f from LDS) ----
    {
      const int r1 = tid >> 4;
      const int cs0 = (tid & 15) * 8;
      const int ac0 = cc * 128 + cs0;
      const char* fb = (const char*)fLds;
      int bo0 = (r1 * 2048 + ac0 * 4) ^ ((r1 & 7) << 4);
      int bo1 = (r1 * 2048 + ac0 * 4 + 16) ^ ((r1 & 7) << 4);
      floatx4 f0 = *(const floatx4*)(fb + bo0);
      floatx4 f1 = *(const floatx4*)(fb + bo1);
      float fv[8] = {f0[0], f0[1], f0[2], f0[3], f1[0], f1[1], f1[2], f1[3]};
#pragma unroll
      for (int s = 0; s < S_N; ++s) {
        const float* sp = sf + ((size_t)s * B_N + b0 + r1) * D_N + ac0;
        floatx4 s0 = *(const floatx4*)(sp);
        floatx4 s1 = *(const floatx4*)(sp + 4);
        const float* ep = emb + s * D_N + ac0;
        floatx4 e0 = *(const floatx4*)(ep);
        floatx4 e1 = *(const floatx4*)(ep + 4);
        float sv[8] = {s0[0], s0[1], s0[2], s0[3], s1[0], s1[1], s1[2], s1[3]};
        float se[8] = {s0[0]+e0[0], s0[1]+e0[1], s0[2]+e0[2], s0[3]+e0[3],
                       s1[0]+e1[0], s1[1]+e1[1], s1[2]+e1[2], s1[3]+e1[3]};
        float ssl = 0.0f, fsl = 0.0f;
#pragma unroll
        for (int q = 0; q < 8; ++q) { ssl += sv[q] * sv[q]; fsl += fv[q] * sv[q]; }
        ssp[s] += ssl; fsp[s] += fsl;
        int rowbase = (s * RB + r1) * 264 + cs0 * 2;
        *(unsigned long long*)((char*)sfe + rowbase)     = pack4(se[0], se[1], se[2], se[3]);
        *(unsigned long long*)((char*)sfe + rowbase + 8) = pack4(se[4], se[5], se[6], se[7]);
      }
    }
    __syncthreads();

    // ---- 2b: R chunk = Q(head h) @ Wk^T; consume with sfe ----
    {
      floatx4 acc2[8];
#pragma unroll
      for (int n = 0; n < 8; ++n) acc2[n] = fz;
      const int row = lane & 15;
#pragma unroll
      for (int ks = 0; ks < 4; ++ks) {
        bf16x8 bfr[8];
#pragma unroll
        for (int n = 0; n < 8; ++n) {
          int a = cc * 128 + n * 16 + (lane & 15);
          bfr[n] = *(const bf16x8*)(Wkb + (size_t)a * 512 + h * 128 + ks * 32 + (lane >> 4) * 8);
        }
        int bo = (row * 1024 + (h * 128 + ks * 32 + (lane >> 4) * 8) * 2) ^ ((row & 7) << 4);
        bf16x8 afr = *(const bf16x8*)((const char*)Qbf + bo);
#pragma unroll
        for (int n = 0; n < 8; ++n)
          acc2[n] = __builtin_amdgcn_mfma_f32_16x16x32_bf16(afr, bfr[n], acc2[n], 0, 0, 0);
      }
#pragma unroll
      for (int s = 0; s < S_N; ++s) {
#pragma unroll
        for (int j = 0; j < 4; ++j) {
          int orow = (lane >> 4) * 4 + j;
          int base = (s * RB + orow) * 264 + (lane & 15) * 2;
          float p = 0.0f;
#pragma unroll
          for (int n = 0; n < 8; ++n) {
            short svv = *(const short*)((const char*)sfe + base + n * 32);
            p += acc2[n][j] * bf2f(svv);
          }
          scp[s][j] += p;
        }
      }
    }
    __syncthreads();
  }

  // ========= phase 3: reductions + finalize combined =========
#pragma unroll
  for (int s = 0; s < S_N; ++s)
#pragma unroll
    for (int j = 0; j < 4; ++j) {
      float v = scp[s][j];
      v += __shfl_xor(v, 1, 64);
      v += __shfl_xor(v, 2, 64);
      v += __shfl_xor(v, 4, 64);
      v += __shfl_xor(v, 8, 64);
      if ((lane & 15) == 0) scLds[(lane >> 4) * 4 + j][wid][s] = v;
    }
  {
    const int r1 = tid >> 4;
#pragma unroll
    for (int s = 0; s < S_N; ++s) {
      float u = ssp[s], v = fsp[s];
      u += __shfl_xor(u, 1, 64); v += __shfl_xor(v, 1, 64);
      u += __shfl_xor(u, 2, 64); v += __shfl_xor(v, 2, 64);
      u += __shfl_xor(u, 4, 64); v += __shfl_xor(v, 4, 64);
      u += __shfl_xor(u, 8, 64); v += __shfl_xor(v, 8, 64);
      if ((tid & 15) == 0) { ssLds[s][r1] = u; fsLds[s][r1] = v; }
    }
  }
  __syncthreads();

  if (tid < RB) {
    const int r = tid;
    const float ffv = ffLds[r];
    const float t = fabsf(temp[0]);

    float amha[S_N] = {0, 0, 0, 0, 0};
    const float inv_mha = 1.0f / (sqrtf(128.0f) * t);
#pragma unroll
    for (int hh = 0; hh < H_N; ++hh) {
      float lg[S_N];
#pragma unroll
      for (int s = 0; s < S_N; ++s) lg[s] = (scLds[r][hh][s] + qtLds[r][hh]) * inv_mha;
      float mx = lg[0];
#pragma unroll
      for (int s = 1; s < S_N; ++s) mx = fmaxf(mx, lg[s]);
      float e[S_N], sum = 0;
#pragma unroll
      for (int s = 0; s < S_N; ++s) { e[s] = __expf(lg[s] - mx); sum += e[s]; }
      float isum = 0.25f / sum;
#pragma unroll
      for (int s = 0; s < S_N; ++s) amha[s] += e[s] * isum;
    }

    float ageo[S_N];
    {
      const float nf = fmaxf(sqrtf(ffv), 1e-12f);
      float g[S_N];
#pragma unroll
      for (int s = 0; s < S_N; ++s) {
        float ns = fmaxf(sqrtf(ssLds[s][r]), 1e-12f);
        float cs0 = fsLds[s][r] / (nf * ns);
        cs0 = fminf(fmaxf(cs0, -1.0f + 1e-7f), 1.0f - 1e-7f);
        g[s] = __expf(-acosf(cs0) / t);
      }
      float mx = g[0];
#pragma unroll
      for (int s = 1; s < S_N; ++s) mx = fmaxf(mx, g[s]);
      float sum = 0;
#pragma unroll
      for (int s = 0; s < S_N; ++s) { ageo[s] = __expf(g[s] - mx); sum += ageo[s]; }
#pragma unroll
      for (int s = 0; s < S_N; ++s) ageo[s] /= sum;
    }

    float acay[S_N];
    {
      const float SQ2 = 1.41421356237309515f;
      const float Aff = 0.72f;
      const float Ass = 0.72f - 0.32f * SQ2;
      const float Afs = -(8.0f + 4.0f * SQ2) / 25.0f;
      float lg[S_N];
#pragma unroll
      for (int s = 0; s < S_N; ++s)
        lg[s] = (Aff * ffv + Ass * ssLds[s][r] + Afs * fsLds[s][r]) / t;
      float mx = lg[0];
#pragma unroll
      for (int s = 1; s < S_N; ++s) mx = fmaxf(mx, lg[s]);
      float sum = 0;
#pragma unroll
      for (int s = 0; s < S_N; ++s) { acay[s] = __expf(lg[s] - mx); sum += acay[s]; }
#pragma unroll
      for (int s = 0; s < S_N; ++s) acay[s] /= sum;
    }

    float w0 = attn_w[0], w1 = attn_w[1], w2 = attn_w[2];
    float wm = fmaxf(w0, fmaxf(w1, w2));
    float e0 = __expf(w0 - wm), e1 = __expf(w1 - wm), e2 = __expf(w2 - wm);
    float wsum = e0 + e1 + e2;
    w0 = e0 / wsum; w1 = e1 / wsum; w2 = e2 / wsum;

    float cb[S_N], csum = 0;
#pragma unroll
    for (int s = 0; s < S_N; ++s) {
      cb[s] = w0 * amha[s] + w1 * ageo[s] + w2 * acay[s];
      csum += cb[s];
    }
    float ic = 1.0f / csum;
#pragma unroll
    for (int s = 0; s < S_N; ++s) comb_out[(size_t)(b0 + r) * S_N + s] = cb[s] * ic;
  }
}

// ---------------- final logits mix (round-2 verbatim, at roofline) ----------------
__global__ __launch_bounds__(256) void k_mix(const float* __restrict__ logits,
                                             const float* __restrict__ comb,
                                             float* __restrict__ out) {
  const int b = blockIdx.x;
  const int c0 = threadIdx.x * 8;
  float cs[S_N];
#pragma unroll
  for (int s = 0; s < S_N; ++s) cs[s] = comb[(size_t)b * S_N + s];
  floatx4 accA = {0, 0, 0, 0}, accB = {0, 0, 0, 0};
#pragma unroll
  for (int s = 0; s < S_N; ++s) {
    const float* lp = logits + ((size_t)s * B_N + b) * C_N + c0;
    floatx4 lA = *(const floatx4*)lp;
    floatx4 lB = *(const floatx4*)(lp + 4);
    accA += lA * cs[s];
    accB += lB * cs[s];
  }
  float* op = out + (size_t)b * C_N + c0;
  *(floatx4*)op = accA;
  *(floatx4*)(op + 4) = accB;
}

extern "C" void kernel_launch(void* const* d_in, const int* in_sizes, int n_in,
                              void* d_out, int out_size, void* d_ws, size_t ws_size,
                              hipStream_t stream) {
  const float* features = (const float*)d_in[0];
  const float* logits   = (const float*)d_in[1];
  const float* sf       = (const float*)d_in[2];
  const float* Wq       = (const float*)d_in[3];
  const float* bq       = (const float*)d_in[4];
  const float* Wk       = (const float*)d_in[5];
  const float* bk       = (const float*)d_in[6];
  const float* emb      = (const float*)d_in[9];
  const float* temp     = (const float*)d_in[10];
  const float* attn_w   = (const float*)d_in[11];

  float* out  = (float*)d_out;
  float* comb = out + (size_t)B_N * C_N;

  char* w = (char*)d_ws;
  short* WqT = (short*)(w);                    // 512*512 bf16 = 0.52 MB
  short* Wkb = (short*)(w + 524288);           // 512*512 bf16 = 0.52 MB

  // 1. weights -> bf16 (WqT transposed)
  k_prep<<<dim3(96), dim3(256), 0, stream>>>(Wq, Wk, WqT, Wkb);
  // 2. mega (RB=16, 2 blocks/CU): cvt + Q + R + scores + stats + softmaxes -> combined
  k_mega<<<dim3(512), dim3(256), 0, stream>>>(features, sf, emb, WqT, Wkb, bq, bk,
                                              temp, attn_w, comb);
  // 3. out[b,c] = sum_s combined[b,s] * logits[s,b,c]  (pure stream, own kernel)
  k_mix<<<dim3(8192), dim3(256), 0, stream>>>(logits, comb, out);
}

// Round 8
// 150.411 us; speedup vs baseline: 1.4703x; 1.1297x over previous
//
#include <hip/hip_runtime.h>
#include <math.h>

#define B_N 8192
#define D_N 512
#define S_N 5
#define C_N 2048
#define H_N 4

typedef __attribute__((ext_vector_type(8))) short bf16x8;
typedef __attribute__((ext_vector_type(4))) float floatx4;

__device__ __forceinline__ float bf2f(short u) {
  union { unsigned int i; float f; } c;
  c.i = ((unsigned int)(unsigned short)u) << 16;
  return c.f;
}
__device__ __forceinline__ short f2bf(float f) {
  union { float f; unsigned int i; } c; c.f = f;
  unsigned int x = c.i;
  x += 0x7fffu + ((x >> 16) & 1u);   // round-to-nearest-even
  return (short)(x >> 16);
}
__device__ __forceinline__ unsigned long long pack4(float a, float b, float c, float d) {
  return (unsigned long long)(unsigned short)f2bf(a)
       | ((unsigned long long)(unsigned short)f2bf(b) << 16)
       | ((unsigned long long)(unsigned short)f2bf(c) << 32)
       | ((unsigned long long)(unsigned short)f2bf(d) << 48);
}

// ---------------- prep: f->bf16 cvt (blocks 0..2047) + WqT transpose (2048..2111)
//                  + Wk->bf16 copy (2112..2143). All independent-block sections. ----------
__global__ __launch_bounds__(256) void k_prep(
    const float* __restrict__ f, const float* __restrict__ Wq,
    const float* __restrict__ Wk, short* __restrict__ fbf,
    short* __restrict__ WqT, short* __restrict__ Wkb) {
  __shared__ float lds[64][65];
  const int bx = blockIdx.x, t = threadIdx.x;
  if (bx < 2048) {
    int i = bx * 256 + t;
    const floatx4* p = (const floatx4*)(f + (size_t)i * 8);
    floatx4 a = p[0], b = p[1];
    *(unsigned long long*)(fbf + (size_t)i * 8)     = pack4(a[0], a[1], a[2], a[3]);
    *(unsigned long long*)(fbf + (size_t)i * 8 + 4) = pack4(b[0], b[1], b[2], b[3]);
  } else if (bx < 2112) {
    const int bb = bx - 2048;
    const int r0 = (bb >> 3) * 64, c0 = (bb & 7) * 64;
#pragma unroll
    for (int i = 0; i < 16; ++i) {
      int r = i * 4 + (t >> 6), c = t & 63;
      lds[r][c] = Wq[(size_t)(r0 + r) * 512 + c0 + c];
    }
    __syncthreads();
#pragma unroll
    for (int i = 0; i < 16; ++i) {
      int cL = i * 4 + (t >> 6), rL = t & 63;
      WqT[(size_t)(c0 + cL) * 512 + r0 + rL] = f2bf(lds[rL][cL]);
    }
  } else {
    const int base = (bx - 2112) * 8192 + t * 4;
#pragma unroll
    for (int i = 0; i < 8; ++i) {
      int idx = base + i * 1024;
      floatx4 v = *(const floatx4*)(Wk + idx);
      *(unsigned long long*)(Wkb + idx) = pack4(v[0], v[1], v[2], v[3]);
    }
  }
}

// ---------------- MFMA GEMM, BM=64 tiles (reshape of the verified 128-tile k_gemm) ------
// 64x128 tile, 4 waves as 2x2 of 32x64, acc[2][4]. Grid: (N/128, M/64, z).
__device__ __forceinline__ void gll(const short* g, short* l) {
  __builtin_amdgcn_global_load_lds(
      (const __attribute__((address_space(1))) unsigned int*)(g),
      (__attribute__((address_space(3))) unsigned int*)(l), 16, 0, 0);
}

__global__ __launch_bounds__(256) void k_gemm64(
    const short* __restrict__ A, int lda,
    const short* __restrict__ BT, int ldb,
    short* __restrict__ O, int ldo,
    const float* __restrict__ bias, int K, int z_koff, int z_coff) {
  __shared__ __align__(16) short As[2][2048];   // 64 rows x 32 k
  __shared__ __align__(16) short Bs[2][4096];   // 128 cols x 32 k

  const int tid = threadIdx.x;
  const int lane = tid & 63;
  const int wid = tid >> 6;
  const int wr = wid >> 1, wc = wid & 1;
  const int row0 = blockIdx.y * 64;
  const int col0 = blockIdx.x * 128;
  const int z = blockIdx.z;
  const int koff = z * z_koff;
  const int ocoff = z * z_coff;

  const int r1 = tid >> 2, hk = tid & 3;
  const short* Ag1 = A + (size_t)(row0 + r1) * lda + koff + hk * 8;
  const short* Bg1 = BT + (size_t)(col0 + r1) * ldb + koff + hk * 8;
  const short* Bg2 = BT + (size_t)(col0 + 64 + r1) * ldb + koff + hk * 8;

  floatx4 acc[2][4];
  const floatx4 zero = {0.0f, 0.0f, 0.0f, 0.0f};
#pragma unroll
  for (int m = 0; m < 2; ++m)
#pragma unroll
    for (int n = 0; n < 4; ++n) acc[m][n] = zero;

  const int NT = K >> 5;
  int cur = 0;

  auto stage = [&](int q, int kb) {
    gll(Ag1 + kb, &As[q][tid * 8]);
    gll(Bg1 + kb, &Bs[q][tid * 8]);
    gll(Bg2 + kb, &Bs[q][tid * 8 + 2048]);
  };

  stage(0, 0);
  __syncthreads();

  for (int t = 0; t < NT; ++t) {
    if (t + 1 < NT) stage(cur ^ 1, (t + 1) * 32);
    bf16x8 af[2], bfr[4];
#pragma unroll
    for (int m = 0; m < 2; ++m)
      af[m] = *(const bf16x8*)&As[cur][(wr * 32 + m * 16 + (lane & 15)) * 32 + (lane >> 4) * 8];
#pragma unroll
    for (int n = 0; n < 4; ++n)
      bfr[n] = *(const bf16x8*)&Bs[cur][(wc * 64 + n * 16 + (lane & 15)) * 32 + (lane >> 4) * 8];
#pragma unroll
    for (int m = 0; m < 2; ++m)
#pragma unroll
      for (int n = 0; n < 4; ++n)
        acc[m][n] = __builtin_amdgcn_mfma_f32_16x16x32_bf16(af[m], bfr[n], acc[m][n], 0, 0, 0);
    __syncthreads();
    cur ^= 1;
  }

#pragma unroll
  for (int m = 0; m < 2; ++m) {
    int rowb = row0 + wr * 32 + m * 16 + (lane >> 4) * 4;
#pragma unroll
    for (int n = 0; n < 4; ++n) {
      int lcol = col0 + wc * 64 + n * 16 + (lane & 15);
      float bv = bias ? bias[lcol] : 0.0f;
      int ocol = ocoff + lcol;
#pragma unroll
      for (int j = 0; j < 4; ++j) {
        O[(size_t)(rowb + j) * ldo + ocol] = f2bf(acc[m][n][j] + bv);
      }
    }
  }
}

// ---------------- fused stats + attention + logits mix (round-5 verbatim, passed) -------
// grid 2048 x 256 thr; wave w -> row b = blockIdx*4 + w. ZERO LDS, ZERO barriers.
__global__ __launch_bounds__(256, 4) void k_fused(
    const float* __restrict__ f, const float* __restrict__ sf,
    const float* __restrict__ emb, const short* __restrict__ Qbf,
    const short* __restrict__ Rbf, const float* __restrict__ bk,
    const float* __restrict__ temp, const float* __restrict__ attn_w,
    const float* __restrict__ logits, float* __restrict__ out,
    float* __restrict__ comb_out) {
  const int lane = threadIdx.x & 63;
  const int wid = threadIdx.x >> 6;
  const int b = blockIdx.x * 4 + wid;
  const int a0 = lane * 8;

  const floatx4* fp = (const floatx4*)(f + (size_t)b * D_N + a0);
  floatx4 fA = fp[0], fB = fp[1];
  float fv[8];
#pragma unroll
  for (int j = 0; j < 4; ++j) { fv[j] = fA[j]; fv[4 + j] = fB[j]; }
  float ffp = 0;
#pragma unroll
  for (int j = 0; j < 8; ++j) ffp += fv[j] * fv[j];

  bf16x8 qv = *(const bf16x8*)(Qbf + (size_t)b * D_N + a0);
  float qbkp = 0;
#pragma unroll
  for (int j = 0; j < 8; ++j) qbkp += bf2f(qv[j]) * bk[a0 + j];

  float rf[H_N][8];
#pragma unroll
  for (int h = 0; h < H_N; ++h) {
    bf16x8 rv = *(const bf16x8*)(Rbf + (size_t)b * 2048 + h * 512 + a0);
#pragma unroll
    for (int j = 0; j < 8; ++j) rf[h][j] = bf2f(rv[j]);
  }

  const int myh = lane >> 4;
  float fs_[S_N], ss_[S_N], sc_[S_N][H_N];

#pragma unroll
  for (int s = 0; s < S_N; ++s) {
    const floatx4* sp = (const floatx4*)(sf + ((size_t)s * B_N + b) * D_N + a0);
    floatx4 sA = sp[0], sB = sp[1];
    const floatx4* ep = (const floatx4*)(emb + (size_t)s * D_N + a0);
    floatx4 eA = ep[0], eB = ep[1];
    float sv[8], se[8];
#pragma unroll
    for (int j = 0; j < 4; ++j) {
      sv[j] = sA[j]; sv[4 + j] = sB[j];
      se[j] = sA[j] + eA[j]; se[4 + j] = sB[j] + eB[j];
    }
    float fsp = 0, ssp = 0;
    float scp[H_N];
#pragma unroll
    for (int h = 0; h < H_N; ++h) scp[h] = (myh == h) ? qbkp : 0.0f;
#pragma unroll
    for (int j = 0; j < 8; ++j) {
      fsp += fv[j] * sv[j];
      ssp += sv[j] * sv[j];
#pragma unroll
      for (int h = 0; h < H_N; ++h) scp[h] += se[j] * rf[h][j];
    }
#pragma unroll
    for (int o = 1; o < 64; o <<= 1) {
      fsp += __shfl_xor(fsp, o, 64);
      ssp += __shfl_xor(ssp, o, 64);
#pragma unroll
      for (int h = 0; h < H_N; ++h) scp[h] += __shfl_xor(scp[h], o, 64);
    }
    fs_[s] = fsp; ss_[s] = ssp;
#pragma unroll
    for (int h = 0; h < H_N; ++h) sc_[s][h] = scp[h];
  }
  float ffv = ffp;
#pragma unroll
  for (int o = 1; o < 64; o <<= 1) ffv += __shfl_xor(ffv, o, 64);

  const float t = fabsf(temp[0]);

  float amha[S_N] = {0, 0, 0, 0, 0};
  const float inv_mha = 1.0f / (sqrtf(128.0f) * t);
#pragma unroll
  for (int h = 0; h < H_N; ++h) {
    float lg[S_N];
#pragma unroll
    for (int s = 0; s < S_N; ++s) lg[s] = sc_[s][h] * inv_mha;
    float mx = lg[0];
#pragma unroll
    for (int s = 1; s < S_N; ++s) mx = fmaxf(mx, lg[s]);
    float e[S_N], sum = 0;
#pragma unroll
    for (int s = 0; s < S_N; ++s) { e[s] = __expf(lg[s] - mx); sum += e[s]; }
    float isum = 0.25f / sum;
#pragma unroll
    for (int s = 0; s < S_N; ++s) amha[s] += e[s] * isum;
  }

  float ageo[S_N];
  {
    const float nf = fmaxf(sqrtf(ffv), 1e-12f);
    float g[S_N];
#pragma unroll
    for (int s = 0; s < S_N; ++s) {
      float ns = fmaxf(sqrtf(ss_[s]), 1e-12f);
      float cs0 = fs_[s] / (nf * ns);
      cs0 = fminf(fmaxf(cs0, -1.0f + 1e-7f), 1.0f - 1e-7f);
      g[s] = __expf(-acosf(cs0) / t);
    }
    float mx = g[0];
#pragma unroll
    for (int s = 1; s < S_N; ++s) mx = fmaxf(mx, g[s]);
    float sum = 0;
#pragma unroll
    for (int s = 0; s < S_N; ++s) { ageo[s] = __expf(g[s] - mx); sum += ageo[s]; }
#pragma unroll
    for (int s = 0; s < S_N; ++s) ageo[s] /= sum;
  }

  float acay[S_N];
  {
    const float SQ2 = 1.41421356237309515f;
    const float Aff = 0.72f;
    const float Ass = 0.72f - 0.32f * SQ2;
    const float Afs = -(8.0f + 4.0f * SQ2) / 25.0f;
    float lg[S_N];
#pragma unroll
    for (int s = 0; s < S_N; ++s)
      lg[s] = (Aff * ffv + Ass * ss_[s] + Afs * fs_[s]) / t;
    float mx = lg[0];
#pragma unroll
    for (int s = 1; s < S_N; ++s) mx = fmaxf(mx, lg[s]);
    float sum = 0;
#pragma unroll
    for (int s = 0; s < S_N; ++s) { acay[s] = __expf(lg[s] - mx); sum += acay[s]; }
#pragma unroll
    for (int s = 0; s < S_N; ++s) acay[s] /= sum;
  }

  float w0 = attn_w[0], w1 = attn_w[1], w2 = attn_w[2];
  float wm = fmaxf(w0, fmaxf(w1, w2));
  float e0 = __expf(w0 - wm), e1 = __expf(w1 - wm), e2 = __expf(w2 - wm);
  float wsum = e0 + e1 + e2;
  w0 = e0 / wsum; w1 = e1 / wsum; w2 = e2 / wsum;

  float cb[S_N], csum = 0;
#pragma unroll
  for (int s = 0; s < S_N; ++s) {
    cb[s] = w0 * amha[s] + w1 * ageo[s] + w2 * acay[s];
    csum += cb[s];
  }
  float ic = 1.0f / csum;
  float cbn[S_N];
#pragma unroll
  for (int s = 0; s < S_N; ++s) cbn[s] = cb[s] * ic;
  if (lane == 0) {
#pragma unroll
    for (int s = 0; s < S_N; ++s) comb_out[(size_t)b * S_N + s] = cbn[s];
  }

  const floatx4 fz = {0.f, 0.f, 0.f, 0.f};
#pragma unroll
  for (int cj = 0; cj < 4; ++cj) {
    const int c0 = cj * 512 + lane * 8;
    floatx4 accA = fz, accB = fz;
#pragma unroll
    for (int s = 0; s < S_N; ++s) {
      const float* lp = logits + ((size_t)s * B_N + b) * C_N + c0;
      floatx4 lA = *(const floatx4*)lp;
      floatx4 lB = *(const floatx4*)(lp + 4);
      accA += lA * cbn[s];
      accB += lB * cbn[s];
    }
    float* op = out + (size_t)b * C_N + c0;
    *(floatx4*)op = accA;
    *(floatx4*)(op + 4) = accB;
  }
}

extern "C" void kernel_launch(void* const* d_in, const int* in_sizes, int n_in,
                              void* d_out, int out_size, void* d_ws, size_t ws_size,
                              hipStream_t stream) {
  const float* features = (const float*)d_in[0];
  const float* logits   = (const float*)d_in[1];
  const float* sf       = (const float*)d_in[2];
  const float* Wq       = (const float*)d_in[3];
  const float* bq       = (const float*)d_in[4];
  const float* Wk       = (const float*)d_in[5];
  const float* bk       = (const float*)d_in[6];
  const float* emb      = (const float*)d_in[9];
  const float* temp     = (const float*)d_in[10];
  const float* attn_w   = (const float*)d_in[11];

  float* out  = (float*)d_out;
  float* comb = out + (size_t)B_N * C_N;

  char* w = (char*)d_ws;
  short* fbf = (short*)(w);                    // 8192*512  bf16 =  8.39 MB
  short* Qbf = (short*)(w + 8388608);          // 8192*512  bf16 =  8.39 MB
  short* Rbf = (short*)(w + 16777216);         // 8192*2048 bf16 = 33.55 MB
  short* WqT = (short*)(w + 50331648);         // 512*512   bf16 =  0.52 MB
  short* Wkb = (short*)(w + 50855936);         // 512*512   bf16 =  0.52 MB

  // 1. f->bf16 + WqT transpose + Wk->bf16 (one kernel, independent block ranges)
  k_prep<<<dim3(2144), dim3(256), 0, stream>>>(features, Wq, Wk, fbf, WqT, Wkb);
  // 2. Q = f @ Wq + bq   (BM=64 tiles, 512 blocks = 2/CU)
  k_gemm64<<<dim3(4, 128, 1), dim3(256), 0, stream>>>(fbf, 512, WqT, 512, Qbf, 512,
                                                      bq, 512, 0, 0);
  // 3. R[b, h*512+a] = sum_j Q[b,h*128+j] * Wk[a,h*128+j]  (2048 blocks)
  k_gemm64<<<dim3(4, 128, 4), dim3(256), 0, stream>>>(Qbf, 512, Wkb, 512, Rbf, 2048,
                                                      (const float*)nullptr, 128, 128, 512);
  // 4. fused stats + attentions + fuse + logits mix (1 wave per row, no LDS/barriers)
  k_fused<<<dim3(2048), dim3(256), 0, stream>>>(features, sf, emb, Qbf, Rbf, bk,
                                                temp, attn_w, logits, out, comb);
}